// Round 11
// baseline (101.325 us; speedup 1.0000x reference)
//
#include <hip/hip_runtime.h>
#include <hip/hip_bf16.h>
#include <math.h>

// Sizes fixed by the reference
#define NN 512
#define NQ 448
#define ND 64          // num_denoising
#define NC 91
#define ED 256
#define NH 8
#define NBLK 256

typedef __attribute__((ext_vector_type(8))) short bf16x8;
typedef __attribute__((ext_vector_type(4))) float f32x4;

struct FreqArg { float fr[32]; };

// Device-global scratch (module-lifetime; every cell rewritten each launch before read)
__device__ int   g_perm[NN];
__device__ float g_c0[NH];
__device__ float g_afull[NN * NH];
__device__ float g_part[64 * 512];  // fold partials [(h*8+cc)*512 + d'] (d'<256: pos, >=256: rank)
__device__ float g_scores[NQ];
__device__ float g_nr[NQ * ED];     // normal_rank = rank_emb @ pre_W^T + pre_b
__device__ __align__(16) unsigned short g_WB[8 * 64 * 8];  // bf16 A-frags [step][lane][elem]
__device__ unsigned g_bar0 = 0, g_bar1 = 0;   // barrier counters; invariant: 0 at entry/exit

__device__ inline unsigned short f2bfbits(float x) {
    __hip_bfloat16 h = __float2bfloat16(x);
    union { __hip_bfloat16 b; unsigned short u; } cv; cv.b = h; return cv.u;
}

// Self-resetting grid barrier. Safe because all NBLK blocks are co-resident
// (256 blocks on 256 CUs, 1 block/CU always fits). Last arriver resets to 0.
__device__ inline void grid_barrier(unsigned* cnt) {
    __syncthreads();
    if (threadIdx.x == 0) {
        __threadfence();   // release prior writes (agent scope)
        unsigned old = __hip_atomic_fetch_add(cnt, 1u, __ATOMIC_ACQ_REL, __HIP_MEMORY_SCOPE_AGENT);
        if (old == NBLK - 1) {
            __hip_atomic_store(cnt, 0u, __ATOMIC_RELEASE, __HIP_MEMORY_SCOPE_AGENT);
        } else {
            while (__hip_atomic_load(cnt, __ATOMIC_ACQUIRE, __HIP_MEMORY_SCOPE_AGENT) != 0u)
                __builtin_amdgcn_s_sleep(2);
        }
        __threadfence();   // acquire other blocks' writes
    }
    __syncthreads();
}

// ---------- phase-1 tasks: 0..223 nr tiles; 224..287 fold partials; 288..295 scores; 296 c0
__device__ void task_p1(int tk, int t, float* smem,
                        const float* __restrict__ logits, const float* __restrict__ attn_W,
                        const float* __restrict__ attn_b, const float* __restrict__ post_W,
                        const float* __restrict__ post_b, const float* __restrict__ pre_W,
                        const float* __restrict__ pre_b, const float* __restrict__ rank_emb) {
    if (tk < 224) {
        // nr tile: 16 q-rows x 32 d-rows, K=256 in LDS
        int q0 = (tk >> 3) * 16, d0 = (tk & 7) * 32;
        float* sP = smem;               // [32][257]
        float* sR = smem + 32 * 257;    // [16][257]
        for (int v = t; v < 32 * 256; v += 512)
            sP[(v >> 8) * 257 + (v & 255)] = pre_W[(size_t)(d0 + (v >> 8)) * ED + (v & 255)];
        for (int v = t; v < 16 * 256; v += 512)
            sR[(v >> 8) * 257 + (v & 255)] = rank_emb[(size_t)(q0 + (v >> 8)) * ED + (v & 255)];
        __syncthreads();
        int q = t >> 5, dl = t & 31;
        float acc = pre_b[d0 + dl];
#pragma unroll 8
        for (int e = 0; e < 256; ++e) acc = fmaf(sR[q * 257 + e], sP[dl * 257 + e], acc);
        g_nr[(size_t)(q0 + q) * ED + d0 + dl] = acc;
    } else if (tk < 288) {
        int f = tk - 224;
        int h = f >> 3, cc = f & 7;
        float* sAW = smem;
        if (t < 32) sAW[t] = attn_W[h * ED + cc * 32 + t];
        __syncthreads();
        float m = 0.f;
        const float* pw = post_W + (size_t)(cc * 32) * 512 + t;
#pragma unroll
        for (int ci = 0; ci < 32; ++ci) m = fmaf(sAW[ci], pw[(size_t)ci * 512], m);
        g_part[(size_t)f * 512 + t] = m;
    } else if (tk < 296) {
        int W = (tk - 288) * 8 + (t >> 6);   // wave id 0..63
        int lane = t & 63;
        for (int qi = 0; qi < 7; ++qi) {
            int q = W * 7 + qi;              // 0..447
            const float* row = logits + (size_t)(ND + q) * NC;
            float m = (lane < NC) ? row[lane] : -INFINITY;
            int c2 = lane + 64;
            if (c2 < NC) m = fmaxf(m, row[c2]);
            for (int off = 32; off > 0; off >>= 1) m = fmaxf(m, __shfl_down(m, off, 64));
            if (lane == 0) g_scores[q] = m;  // sigmoid(max)==max(sigmoid): rank raw logits
        }
    } else {
        int h = t >> 6, lane = t & 63;
        float v = 0.f;
#pragma unroll
        for (int k = 0; k < 4; ++k) {
            int c = lane + 64 * k;
            v = fmaf(attn_W[h * ED + c], post_b[c], v);
        }
        for (int off = 32; off > 0; off >>= 1) v += __shfl_down(v, off, 64);
        if (lane == 0) g_c0[h] = attn_b[h] + v;
    }
}

// ---------- phase-2 tasks: 0..55 afull tiles (8 q); 56..57 WB pack; 58 argsort
__device__ void task_p2(int bid, int t, float* smem, float* __restrict__ out2) {
    if (bid < 56) {
        float* sW = smem;             // [8][260]  w2a (redundant per-block reduce of partials)
        float* sN = smem + 8 * 260;   // [8][260]  nr rows of this q-tile
        int q0 = bid * 8;
        for (int v = t; v < 2048; v += 512) {
            int h = v >> 8, d = v & 255;
            float s = 0.f;
#pragma unroll
            for (int cc = 0; cc < 8; ++cc) s += g_part[(size_t)(h * 8 + cc) * 512 + 256 + d];
            sW[h * 260 + d] = s;
        }
        for (int v = t; v < 2048; v += 512)
            sN[(v >> 8) * 260 + (v & 255)] = g_nr[(size_t)(q0 + (v >> 8)) * ED + (v & 255)];
        __syncthreads();
        int o = t >> 3, sub = t & 7;       // 64 outputs (8q x 8h), 8 threads each
        int q = o >> 3, h = o & 7;
        float a = 0.f;
#pragma unroll 8
        for (int e2 = 0; e2 < 32; ++e2) {
            int e = sub + 8 * e2;
            a = fmaf(sN[q * 260 + e], sW[h * 260 + e], a);
        }
        a += __shfl_xor(a, 1, 64);
        a += __shfl_xor(a, 2, 64);
        a += __shfl_xor(a, 4, 64);
        if (sub == 0) g_afull[(size_t)(ND + q0 + q) * NH + h] = a;
    } else if (bid < 58) {
        // WB pack straight from fold partials
        for (int vv = t; vv < 2048; vv += 512) {
            int v = (bid - 56) * 2048 + vv;
            int s = v >> 9;
            int lane = (v >> 3) & 63;
            int ii = v & 7;
            int g = lane >> 4, hh = lane & 15;
            int k = s * 4 + (ii >> 1), r = ii & 1;
            int d = g * 64 + 2 * k + r;
            float w = 0.f;
            if (hh < NH) {
#pragma unroll
                for (int cc = 0; cc < 8; ++cc) w += g_part[(size_t)(hh * 8 + cc) * 512 + d];
            }
            g_WB[v] = f2bfbits(w);
        }
    } else if (bid == 58) {
        // stable descending argsort by rank-count
        float* sc = smem;
        for (int v = t; v < NQ; v += 512) sc[v] = g_scores[v];
        __syncthreads();
        if (t < NQ) {
            float s1 = sc[t];
            int r1 = 0;
            for (int j = 0; j < NQ; ++j) {
                float sj = sc[j];
                r1 += ((sj > s1) || (sj == s1 && j < t)) ? 1 : 0;
            }
            g_perm[ND + r1] = ND + t;
            out2[ND + r1] = (float)(ND + t);
        }
        if (t < ND) {
            g_perm[t] = t;
            out2[t] = (float)t;
            for (int h = 0; h < NH; ++h) g_afull[t * NH + h] = 0.f;
        }
    }
}

// ---------- fused kernel
__global__ __launch_bounds__(512) void fused_all(const float* __restrict__ boxes,
                                                 const float* __restrict__ logits,
                                                 const float* __restrict__ rank_emb,
                                                 const float* __restrict__ pre_W,
                                                 const float* __restrict__ pre_b,
                                                 const float* __restrict__ post_W,
                                                 const float* __restrict__ post_b,
                                                 const float* __restrict__ attn_W,
                                                 const float* __restrict__ attn_b,
                                                 FreqArg fa,
                                                 float* __restrict__ out) {
    __shared__ __align__(16) float smem[48 * 257];   // 49.3 KB, reused across phases
    int bid = blockIdx.x;
    int t = threadIdx.x;
    float* out2 = out + (size_t)NH * NN * NN;        // rank_indices region

    // ---- phase 1 (blocks 0..40 run a second task)
    task_p1(bid, t, smem, logits, attn_W, attn_b, post_W, post_b, pre_W, pre_b, rank_emb);
    if (bid + 256 < 297) {
        __syncthreads();
        task_p1(bid + 256, t, smem, logits, attn_W, attn_b, post_W, post_b, pre_W, pre_b, rank_emb);
    }
    grid_barrier(&g_bar0);

    // ---- phase 2
    task_p2(bid, t, smem, out2);
    grid_barrier(&g_bar1);

    // ---- phase 3: MFMA main. Block = 2 i-rows; wave = (i, j-quarter); 8 tiles of 16 pairs.
    ((uint4*)smem)[t] = ((const uint4*)g_WB)[t];     // sWB: 8 KB
    int* sPerm = (int*)(smem + 2048);
    sPerm[t] = g_perm[t];
    float* sAf = smem + 2560;                        // afull: 16 KB
    for (int v = t; v < NN * NH; v += 512) sAf[v] = g_afull[v];
    __syncthreads();

    const bf16x8* sWB = (const bf16x8*)smem;         // [8][64]
    int wv = t >> 6, lane = t & 63;
    int g = lane >> 4, r = lane & 15;
    int i = 2 * bid + (wv >> 2);
    int q4 = wv & 3;

    float4 b1p = ((const float4*)boxes)[i];
    float4 b1s = b1p;
    if (i >= ND) b1s = ((const float4*)boxes)[sPerm[i]];
    const float* cb = g_c0 + g * 4;
    const float* ai_pl = sAf + i * NH + g * 4;
    const float eps = 1e-5f;

#pragma unroll
    for (int k = 0; k < 8; ++k) {
        int j0 = q4 * 128 + k * 16;
        int j = j0 + r;
        bool prm = (i >= ND) && (j0 >= ND);          // permute ONLY the [64:,64:] block
        float4 b1 = prm ? b1s : b1p;
        int pj = prm ? sPerm[j] : j;
        float4 b2 = ((const float4*)boxes)[pj];

        float ft;
        if (g == 0)      ft = logf(fabsf(b1.x - b2.x) / (b1.z + eps) + 1.0f);
        else if (g == 1) ft = logf(fabsf(b1.y - b2.y) / (b1.w + eps) + 1.0f);
        else if (g == 2) ft = logf((b1.z + eps) / (b2.z + eps));
        else             ft = logf((b1.w + eps) / (b2.w + eps));

        f32x4 acc = {0.f, 0.f, 0.f, 0.f};
#pragma unroll
        for (int s = 0; s < 8; ++s) {
            bf16x8 bfrag;
#pragma unroll
            for (int a = 0; a < 4; ++a) {
                float rev = ft * fa.fr[s * 4 + a];
                rev -= floorf(rev);
                float sv = __builtin_amdgcn_sinf(rev);   // sin(2*pi*rev)
                float cv = __builtin_amdgcn_cosf(rev);
                bfrag[2 * a]     = (short)f2bfbits(sv);
                bfrag[2 * a + 1] = (short)f2bfbits(cv);
            }
            acc = __builtin_amdgcn_mfma_f32_16x16x32_bf16(sWB[s * 64 + lane], bfrag, acc, 0, 0, 0);
        }

        if (g < 2) {
            const float* aj = sAf + j * NH + g * 4;
#pragma unroll
            for (int qq = 0; qq < 4; ++qq) {
                int h = g * 4 + qq;
                float v = acc[qq] + cb[qq] + ai_pl[qq] + aj[qq];
                v = v > 0.f ? v : 0.f;
                out[(size_t)h * (NN * NN) + i * NN + j] = v;
            }
        }
    }
}

extern "C" void kernel_launch(void* const* d_in, const int* in_sizes, int n_in,
                              void* d_out, int out_size, void* d_ws, size_t ws_size,
                              hipStream_t stream) {
    const float* boxes    = (const float*)d_in[0];
    const float* logits   = (const float*)d_in[1];
    const float* rank_emb = (const float*)d_in[2];
    const float* pre_W    = (const float*)d_in[3];
    const float* pre_b    = (const float*)d_in[4];
    const float* post_W   = (const float*)d_in[5];
    const float* post_b   = (const float*)d_in[6];
    const float* attn_W   = (const float*)d_in[7];
    const float* attn_b   = (const float*)d_in[8];
    float* out = (float*)d_out;

    FreqArg fa;
    for (int k = 0; k < 32; ++k)
        fa.fr[k] = (float)(100.0 / (2.0 * M_PI) / pow(10000.0, (double)k / 32.0));

    fused_all<<<NBLK, 512, 0, stream>>>(boxes, logits, rank_emb, pre_W, pre_b,
                                        post_W, post_b, attn_W, attn_b, fa, out);
}

// Round 12
// 51.034 us; speedup vs baseline: 1.9854x; 1.9854x over previous
//
#include <hip/hip_runtime.h>
#include <hip/hip_bf16.h>
#include <math.h>

// Sizes fixed by the reference
#define NN 512
#define NQ 448
#define ND 64          // num_denoising
#define NC 91
#define ED 256
#define NH 8

typedef __attribute__((ext_vector_type(8))) short bf16x8;
typedef __attribute__((ext_vector_type(4))) float f32x4;

struct FreqArg { float fr[32]; };

// Device-global scratch (every cell rewritten each launch before read; WB hh>=8 lanes zeroed each launch)
__device__ int   g_perm[NN];
__device__ float g_c0[NH];
__device__ float g_afull[NN * NH];
__device__ __align__(16) unsigned short g_WB[8 * 64 * 8];  // bf16 A-frags [step][lane][elem]

__device__ inline unsigned short f2bfbits(float x) {
    __hip_bfloat16 h = __float2bfloat16(x);
    union { __hip_bfloat16 b; unsigned short u; } cv; cv.b = h; return cv.u;
}

// ---------------- Kernel P: 9 blocks x 512. Block h<8 owns head h end-to-end (intra-block deps only).
// Block 8: scores -> argsort -> perm/rank_indices; zero WB pad lanes.
__global__ __launch_bounds__(512) void precomp(const float* __restrict__ logits,
                                               const float* __restrict__ attn_W,
                                               const float* __restrict__ attn_b,
                                               const float* __restrict__ post_W,
                                               const float* __restrict__ post_b,
                                               const float* __restrict__ pre_W,
                                               const float* __restrict__ pre_b,
                                               const float* __restrict__ rank_emb,
                                               float* __restrict__ out2) {
    __shared__ float sAW[ED];      // attn_W row
    __shared__ float sFold[512];   // [0,256): pos weights by d'; [256,512): w2a[d]
    __shared__ float sU2[512];     // split-half partial u
    __shared__ float sU[ED];       // u[h,e]
    __shared__ float sc[NQ];       // scores (block 8)
    __shared__ float sB2a;
    int bid = blockIdx.x, t = threadIdx.x;

    if (bid < NH) {
        int h = bid;
        if (t < ED) sAW[t] = attn_W[h * ED + t];
        __syncthreads();

        // fold: m[d'] = sum_c attn_W[h,c] * post_W[c*512 + d']   (coalesced over t)
        float m = 0.f;
        const float* pw = post_W + t;
#pragma unroll 16
        for (int c = 0; c < ED; ++c) m = fmaf(sAW[c], pw[(size_t)c * 512], m);
        sFold[t] = m;
        __syncthreads();

        // u[e] = sum_d w2a[d] * pre_W[d*256 + e], split over halves of d
        {
            int e = t & 255, half = t >> 8;
            float acc = 0.f;
            const float* pwc = pre_W + (size_t)(half * 128) * ED + e;
#pragma unroll 16
            for (int dl = 0; dl < 128; ++dl)
                acc = fmaf(sFold[256 + half * 128 + dl], pwc[(size_t)dl * ED], acc);
            sU2[half * 256 + e] = acc;
        }
        // c0 (wave 0) and b2a (wave 1)
        if (t < 64) {
            float v = 0.f;
#pragma unroll
            for (int k = 0; k < 4; ++k) v = fmaf(sAW[t + 64 * k], post_b[t + 64 * k], v);
            for (int off = 32; off > 0; off >>= 1) v += __shfl_down(v, off, 64);
            if (t == 0) g_c0[h] = attn_b[h] + v;
        } else if (t < 128) {
            int l = t - 64;
            float v = 0.f;
#pragma unroll
            for (int k = 0; k < 4; ++k) v = fmaf(sFold[256 + l + 64 * k], pre_b[l + 64 * k], v);
            for (int off = 32; off > 0; off >>= 1) v += __shfl_down(v, off, 64);
            if (l == 0) sB2a = v;
        }
        // WB pack for this head: lane = g*16+h, value = fold_pos[d = g*64 + 2k + r], k=s*4+(ii>>1), r=ii&1
        if (t < 256) {
            int s = t >> 5, g = (t >> 3) & 3, ii = t & 7;
            int d = g * 64 + ((s * 4 + (ii >> 1)) << 1) + (ii & 1);
            g_WB[s * 512 + (g * 16 + h) * 8 + ii] = f2bfbits(sFold[d]);
        }
        if (t < ND) g_afull[t * NH + h] = 0.f;   // denoising rows: rank_rel contribution = 0
        __syncthreads();
        if (t < ED) sU[t] = sU2[t] + sU2[256 + t];
        __syncthreads();

        // afull[ND+q, h] = b2a + sum_e remb[q,e] * u[e]; 32 q x 16 subs per pass
        float b2a = sB2a;
        for (int pass = 0; pass < 14; ++pass) {
            int q = pass * 32 + (t >> 4);
            int sub = t & 15;
            const float* re = rank_emb + (size_t)q * ED;
            float a = 0.f;
#pragma unroll
            for (int kk = 0; kk < 16; ++kk) a = fmaf(re[sub + 16 * kk], sU[sub + 16 * kk], a);
            a += __shfl_xor(a, 1, 64);
            a += __shfl_xor(a, 2, 64);
            a += __shfl_xor(a, 4, 64);
            a += __shfl_xor(a, 8, 64);
            if (sub == 0) g_afull[(size_t)(ND + q) * NH + h] = b2a + a;
        }
    } else {
        // zero WB lanes with hh >= 8 (deterministic every launch)
        for (int v = t; v < 4096; v += 512) {
            int lane = (v >> 3) & 63;
            if ((lane & 15) >= NH) g_WB[v] = 0;
        }
        // scores: 8 waves x 56 queries, coalesced row reads + shfl max-reduce.
        // sigmoid(max) == max(sigmoid) (monotone) -> rank raw max-logits.
        int W = t >> 6, lane = t & 63;
        for (int qi = 0; qi < 56; ++qi) {
            int q = W * 56 + qi;
            const float* row = logits + (size_t)(ND + q) * NC;
            float m = (lane < NC) ? row[lane] : -INFINITY;
            int c2 = lane + 64;
            if (c2 < NC) m = fmaxf(m, row[c2]);
            for (int off = 32; off > 0; off >>= 1) m = fmaxf(m, __shfl_down(m, off, 64));
            if (lane == 0) sc[q] = m;
        }
        __syncthreads();
        // stable descending argsort by rank-count
        if (t < NQ) {
            float s1 = sc[t];
            int r1 = 0;
            for (int j = 0; j < NQ; ++j) {
                float sj = sc[j];
                r1 += ((sj > s1) || (sj == s1 && j < t)) ? 1 : 0;
            }
            g_perm[ND + r1] = ND + t;
            out2[ND + r1] = (float)(ND + t);
        }
        if (t < ND) {
            g_perm[t] = t;
            out2[t] = (float)t;
        }
    }
}

// ---------------- Kernel M: MFMA main (R10-proven). Wave = 16 pairs; A = weights (rows = heads),
// B = in-register sine features (cols = pairs); 8 x K=32 steps.
__global__ __launch_bounds__(256) void relation_main(const float* __restrict__ boxes,
                                                     FreqArg fa,
                                                     float* __restrict__ out) {
    __shared__ bf16x8 sWB[8][64];
    int t = threadIdx.x;
    ((uint4*)sWB)[t]       = ((const uint4*)g_WB)[t];
    ((uint4*)sWB)[t + 256] = ((const uint4*)g_WB)[t + 256];
    __syncthreads();

    int wave = t >> 6, lane = t & 63;
    int g = lane >> 4, r = lane & 15;
    int i = blockIdx.x >> 3;
    int j = ((blockIdx.x & 7) << 6) + (wave << 4) + r;

    int pi = i, pj = j;
    if (i >= ND && j >= ND) { pi = g_perm[i]; pj = g_perm[j]; }   // permute ONLY the [64:,64:] block
    float4 b1 = ((const float4*)boxes)[pi];
    float4 b2 = ((const float4*)boxes)[pj];
    const float eps = 1e-5f;
    float ft;
    if (g == 0)      ft = logf(fabsf(b1.x - b2.x) / (b1.z + eps) + 1.0f);
    else if (g == 1) ft = logf(fabsf(b1.y - b2.y) / (b1.w + eps) + 1.0f);
    else if (g == 2) ft = logf((b1.z + eps) / (b2.z + eps));
    else             ft = logf((b1.w + eps) / (b2.w + eps));

    f32x4 acc = {0.f, 0.f, 0.f, 0.f};
#pragma unroll
    for (int s = 0; s < 8; ++s) {
        bf16x8 bfrag;
#pragma unroll
        for (int a = 0; a < 4; ++a) {
            float rev = ft * fa.fr[s * 4 + a];
            rev -= floorf(rev);
            float sv = __builtin_amdgcn_sinf(rev);   // sin(2*pi*rev)
            float cv = __builtin_amdgcn_cosf(rev);
            bfrag[2 * a]     = (short)f2bfbits(sv);
            bfrag[2 * a + 1] = (short)f2bfbits(cv);
        }
        acc = __builtin_amdgcn_mfma_f32_16x16x32_bf16(sWB[s][lane], bfrag, acc, 0, 0, 0);
    }

    // D: row = g*4 + q (head, valid < 8 -> g < 2), col = r (pair)
    if (g < 2) {
        float4 cb = *(const float4*)(g_c0 + g * 4);
        float4 ai = *(const float4*)(g_afull + i * NH + g * 4);
        float4 aj = *(const float4*)(g_afull + j * NH + g * 4);
        const float* cbp = (const float*)&cb;
        const float* aip = (const float*)&ai;
        const float* ajp = (const float*)&aj;
#pragma unroll
        for (int q = 0; q < 4; ++q) {
            int h = g * 4 + q;
            float v = acc[q] + cbp[q] + aip[q] + ajp[q];
            v = v > 0.f ? v : 0.f;
            out[(size_t)h * (NN * NN) + i * NN + j] = v;
        }
    }
}

extern "C" void kernel_launch(void* const* d_in, const int* in_sizes, int n_in,
                              void* d_out, int out_size, void* d_ws, size_t ws_size,
                              hipStream_t stream) {
    const float* boxes    = (const float*)d_in[0];
    const float* logits   = (const float*)d_in[1];
    const float* rank_emb = (const float*)d_in[2];
    const float* pre_W    = (const float*)d_in[3];
    const float* pre_b    = (const float*)d_in[4];
    const float* post_W   = (const float*)d_in[5];
    const float* post_b   = (const float*)d_in[6];
    const float* attn_W   = (const float*)d_in[7];
    const float* attn_b   = (const float*)d_in[8];
    float* out = (float*)d_out;

    precomp<<<NH + 1, 512, 0, stream>>>(logits, attn_W, attn_b, post_W, post_b,
                                        pre_W, pre_b, rank_emb,
                                        out + (size_t)NH * NN * NN);

    FreqArg fa;
    for (int k = 0; k < 32; ++k)
        fa.fr[k] = (float)(100.0 / (2.0 * M_PI) / pow(10000.0, (double)k / 32.0));

    relation_main<<<4096, 256, 0, stream>>>(boxes, fa, out);
}